// Round 6
// baseline (72.689 us; speedup 1.0000x reference)
//
#include <hip/hip_runtime.h>
#include <hip/hip_bf16.h>
#include <math.h>

// out[n,:] = s1 .* FWHT( (u/4096) .* FWHT( s2 .* x[n,:] ) ),
// u = g_mu + softplus(g_rho)*epsilon, FWHT = unnormalized Walsh-Hadamard.
//
// R6: persistent radix-16 row-pair kernel.
//  - 1280 blocks (5 per CU = LDS residency cap), grid-stride over row pairs
//  - one-pair-ahead register prefetch of x (8 b128 in flight during compute)
//  - u precomputed AND thread-transposed (u_perm[t*16+j] = u[j*256+t]) so the
//    diagonal multiply is 4 b128 loads; s2/u/s1 issued before the prefetch so
//    counted vmcnt waits keep the prefetch in flight
//  - 6 in-register fwht16 passes on f2 (v_pk_add_f32), two rows packed
//  - 4 XOR-swizzled LDS rotations, 2 __syncthreads per pair (rot1/rot4 are
//    wave-local; cross-pair slab reuse is same-wave DS-FIFO ordered)

#define WHVI_D 4096
#define NBLK 1280   // 5 blocks/CU * 256 CUs

typedef float f2 __attribute__((ext_vector_type(2)));

__device__ __forceinline__ void fwht16(f2 v[16]) {
#pragma unroll
    for (int s = 1; s < 16; s <<= 1) {
#pragma unroll
        for (int i = 0; i < 16; ++i) {
            if ((i & s) == 0) {
                f2 a = v[i], b = v[i | s];
                v[i] = a + b;       // v_pk_add_f32
                v[i | s] = a - b;
            }
        }
    }
}

__global__ __launch_bounds__(256)
void u_precompute_kernel(const float* __restrict__ g_mu,
                         const float* __restrict__ g_rho,
                         const float* __restrict__ g_eps,
                         float* __restrict__ u_perm) {
    int k = blockIdx.x * 256 + threadIdx.x;  // 0..4095, coalesced reads
    float rho = g_rho[k];
    float sp = fmaxf(rho, 0.0f) + __logf(1.0f + __expf(-fabsf(rho)));
    float uu = (g_mu[k] + sp * g_eps[k]) * (1.0f / 4096.0f);
    // u index k = j*256 + t  ->  store at t*16 + j (per-thread contiguous)
    u_perm[(k & 255) * 16 + (k >> 8)] = uu;
}

__device__ __forceinline__ void lgkm_fence() {
    asm volatile("s_waitcnt lgkmcnt(0)" ::: "memory");
    __builtin_amdgcn_sched_barrier(0);
}

__device__ __forceinline__ void load_pair(float4 a0[4], float4 a1[4],
                                          const float* __restrict__ x,
                                          size_t b0, size_t b1, int t) {
    const float4* p0 = reinterpret_cast<const float4*>(x + b0 + t * 16);
    const float4* p1 = reinterpret_cast<const float4*>(x + b1 + t * 16);
#pragma unroll
    for (int c = 0; c < 4; ++c) { a0[c] = p0[c]; a1[c] = p1[c]; }
}

// LDS layout in f2 units: A(c2,c1,c0) = c2*256 + c1*16 + (c0 ^ (c1 & 14)).
// All four rotation patterns hand-checked uniform across banks (R5 measured
// SQ_LDS_BANK_CONFLICT at the trivial 256 cyc/block level).

__device__ __forceinline__ void pair_body(const float4 a0[4], const float4 a1[4],
                                          f2* __restrict__ lds,
                                          const float* __restrict__ s1,
                                          const float* __restrict__ s2,
                                          const float* __restrict__ u_perm,
                                          float* __restrict__ out,
                                          size_t b0, size_t b1, bool r1_valid,
                                          int t, int P, int Q) {
    // Issue all parameter loads FIRST (so later waits don't drain the next
    // pair's prefetch, which the caller issues after these).
    const float4* s2v = reinterpret_cast<const float4*>(s2 + t * 16);
    const float4* upv = reinterpret_cast<const float4*>(u_perm + t * 16);
    const float4* s1v = reinterpret_cast<const float4*>(s1 + t * 16);
    float4 s2r[4], upr[4], s1r[4];
#pragma unroll
    for (int c = 0; c < 4; ++c) s2r[c] = s2v[c];
#pragma unroll
    for (int c = 0; c < 4; ++c) upr[c] = upv[c];
#pragma unroll
    for (int c = 0; c < 4; ++c) s1r[c] = s1v[c];

    f2 v[16];
    // ---- scale by s2, pack rows into f2 lanes ----
#pragma unroll
    for (int c = 0; c < 4; ++c) {
        float4 a = a0[c], b = a1[c], s = s2r[c];
        v[4 * c + 0] = f2{a.x * s.x, b.x * s.x};
        v[4 * c + 1] = f2{a.y * s.y, b.y * s.y};
        v[4 * c + 2] = f2{a.z * s.z, b.z * s.z};
        v[4 * c + 3] = f2{a.w * s.w, b.w * s.w};
    }

    // ---- pass 1: digit d0 ----
    fwht16(v);

    // ---- rot1 (wave-local slab): write (P,Q,j) b128, read (P,j,Q) b64 ----
#pragma unroll
    for (int c = 0; c < 8; ++c) {
        int a4 = P * 256 + Q * 16 + ((2 * c) ^ (Q & 14));
        *reinterpret_cast<float4*>(&lds[a4]) =
            make_float4(v[2 * c].x, v[2 * c].y, v[2 * c + 1].x, v[2 * c + 1].y);
    }
    lgkm_fence();
#pragma unroll
    for (int j = 0; j < 16; ++j)
        v[j] = lds[P * 256 + j * 16 + (Q ^ (j & 14))];

    // ---- pass 2: digit d1 ----
    fwht16(v);

    // ---- rot2: write back same addrs (WAR, wave-local), bar, read cross ----
#pragma unroll
    for (int j = 0; j < 16; ++j)
        lds[P * 256 + j * 16 + (Q ^ (j & 14))] = v[j];
    __syncthreads();
#pragma unroll
    for (int j = 0; j < 16; ++j)
        v[j] = lds[j * 256 + P * 16 + (Q ^ (P & 14))];

    // ---- pass 3: digit d2 -> FWHT#1 done; v[j] = y[j*256 + t] ----
    fwht16(v);

    // ---- diagonal u: u_perm[t*16+j] == u[j*256+t], b128-loaded above ----
#pragma unroll
    for (int c = 0; c < 4; ++c) {
        v[4 * c + 0] *= upr[c].x;
        v[4 * c + 1] *= upr[c].y;
        v[4 * c + 2] *= upr[c].z;
        v[4 * c + 3] *= upr[c].w;
    }

    // ---- pass 4: digit e2 ----
    fwht16(v);

    // ---- rot3: write cross (same addrs as rot2-read), bar, read wave-local ----
#pragma unroll
    for (int j = 0; j < 16; ++j)
        lds[j * 256 + P * 16 + (Q ^ (P & 14))] = v[j];
    __syncthreads();
#pragma unroll
    for (int j = 0; j < 16; ++j)
        v[j] = lds[P * 256 + j * 16 + (Q ^ (j & 14))];

    // ---- pass 5: digit e1 ----
    fwht16(v);

    // ---- rot4 (wave-local): write back, fence, read (P,Q,j) b128 ----
#pragma unroll
    for (int j = 0; j < 16; ++j)
        lds[P * 256 + j * 16 + (Q ^ (j & 14))] = v[j];
    lgkm_fence();
#pragma unroll
    for (int c = 0; c < 8; ++c) {
        int a4 = P * 256 + Q * 16 + ((2 * c) ^ (Q & 14));
        float4 tt = *reinterpret_cast<const float4*>(&lds[a4]);
        v[2 * c]     = f2{tt.x, tt.y};
        v[2 * c + 1] = f2{tt.z, tt.w};
    }

    // ---- pass 6: digit e0 -> natural order, element 16t + j ----
    fwht16(v);

    // ---- s1 scale + store both rows ----
    {
        float4* o0 = reinterpret_cast<float4*>(out + b0 + t * 16);
        float4* o1 = reinterpret_cast<float4*>(out + b1 + t * 16);
#pragma unroll
        for (int c = 0; c < 4; ++c) {
            float4 s = s1r[c];
            o0[c] = make_float4(v[4 * c + 0].x * s.x, v[4 * c + 1].x * s.y,
                                v[4 * c + 2].x * s.z, v[4 * c + 3].x * s.w);
            if (r1_valid)
                o1[c] = make_float4(v[4 * c + 0].y * s.x, v[4 * c + 1].y * s.y,
                                    v[4 * c + 2].y * s.z, v[4 * c + 3].y * s.w);
        }
    }
}

__global__ __launch_bounds__(256)
void whvi_persist_kernel(const float* __restrict__ x,
                         const float* __restrict__ s1,
                         const float* __restrict__ s2,
                         const float* __restrict__ u_perm,
                         float* __restrict__ out,
                         int nrows) {
    __shared__ __align__(16) f2 lds[WHVI_D];  // 32 KB

    const int t = threadIdx.x;
    const int P = t >> 4;
    const int Q = t & 15;
    const int npairs = (nrows + 1) >> 1;

    int p = blockIdx.x;
    if (p >= npairs) return;

    auto bases = [&](int pr, size_t& b0, size_t& b1, bool& rv) {
        int r0 = pr * 2;
        rv = (r0 + 1 < nrows);
        b0 = (size_t)r0 * WHVI_D;
        b1 = (size_t)(r0 + (rv ? 1 : 0)) * WHVI_D;
    };

    float4 A0[4], A1[4], B0[4], B1[4];
    size_t b0, b1; bool rv;
    bases(p, b0, b1, rv);
    load_pair(A0, A1, x, b0, b1, t);

    bool useA = true;
    for (;;) {
        int pn = p + NBLK;
        size_t nb0 = 0, nb1 = 0; bool nrv = false;
        if (pn < npairs) {
            bases(pn, nb0, nb1, nrv);
            // prefetch next pair (issued AFTER body's param loads? No —
            // issued here, BEFORE body. Body's param loads are L2-hot and
            // their waits count these 8 as outstanding-but-unwaited.)
            if (useA) load_pair(B0, B1, x, nb0, nb1, t);
            else      load_pair(A0, A1, x, nb0, nb1, t);
        }
        if (useA) pair_body(A0, A1, lds, s1, s2, u_perm, out, b0, b1, rv, t, P, Q);
        else      pair_body(B0, B1, lds, s1, s2, u_perm, out, b0, b1, rv, t, P, Q);
        if (pn >= npairs) break;
        p = pn; b0 = nb0; b1 = nb1; rv = nrv; useA = !useA;
    }
}

extern "C" void kernel_launch(void* const* d_in, const int* in_sizes, int n_in,
                              void* d_out, int out_size, void* d_ws, size_t ws_size,
                              hipStream_t stream) {
    const float* x     = (const float*)d_in[0];
    const float* s1    = (const float*)d_in[1];
    const float* s2    = (const float*)d_in[2];
    const float* g_mu  = (const float*)d_in[3];
    const float* g_rho = (const float*)d_in[4];
    const float* g_eps = (const float*)d_in[5];
    // d_in[6] is H — unused; the FWHT realizes it exactly.
    float* out = (float*)d_out;

    const int nrows = in_sizes[0] / WHVI_D;  // 8192

    float* u_perm = (float*)d_ws;  // 16 KB of workspace
    u_precompute_kernel<<<WHVI_D / 256, 256, 0, stream>>>(g_mu, g_rho, g_eps, u_perm);

    const int npairs = (nrows + 1) / 2;
    const int nblk = npairs < NBLK ? npairs : NBLK;
    whvi_persist_kernel<<<nblk, 256, 0, stream>>>(x, s1, s2, u_perm, out, nrows);
}

// Round 7
// 71.475 us; speedup vs baseline: 1.0170x; 1.0170x over previous
//
#include <hip/hip_runtime.h>
#include <hip/hip_bf16.h>
#include <math.h>

// out[n,:] = s1 .* FWHT( (u/4096) .* FWHT( s2 .* x[n,:] ) ),
// u = g_mu + softplus(g_rho)*epsilon, FWHT = unnormalized Walsh-Hadamard.
//
// R7: persistent radix-16 row-pair kernel with CORRECT prefetch ordering.
//  R6 bug: next-pair x-loads were issued BEFORE the body's param loads, so
//  the pack-time wait (vmcnt retires oldest-first) drained the prefetch at
//  body START -> prefetch added latency instead of hiding it.
//  Fix: s2 loaded once before the loop (oldest), prefetch issued next,
//  u_perm/s1 loaded MID-BODY (their waits land ~1500+ cyc after prefetch
//  issue, when the prefetch has already completed naturally).
//  Pack waits vmcnt(8): prefetch survives.
//  NBLK = 1024 -> exactly 4 pairs per block (balanced tail; R6's 1280 was
//  ragged 3.2).

#define WHVI_D 4096
#define NBLK 1024   // 4 blocks/CU * 256 CUs; 4096 pairs -> exactly 4 each

typedef float f2 __attribute__((ext_vector_type(2)));

__device__ __forceinline__ void fwht16(f2 v[16]) {
#pragma unroll
    for (int s = 1; s < 16; s <<= 1) {
#pragma unroll
        for (int i = 0; i < 16; ++i) {
            if ((i & s) == 0) {
                f2 a = v[i], b = v[i | s];
                v[i] = a + b;       // v_pk_add_f32
                v[i | s] = a - b;
            }
        }
    }
}

__global__ __launch_bounds__(256)
void u_precompute_kernel(const float* __restrict__ g_mu,
                         const float* __restrict__ g_rho,
                         const float* __restrict__ g_eps,
                         float* __restrict__ u_perm) {
    int k = blockIdx.x * 256 + threadIdx.x;  // 0..4095, coalesced reads
    float rho = g_rho[k];
    float sp = fmaxf(rho, 0.0f) + __logf(1.0f + __expf(-fabsf(rho)));
    float uu = (g_mu[k] + sp * g_eps[k]) * (1.0f / 4096.0f);
    // u index k = j*256 + t  ->  store at t*16 + j (per-thread contiguous)
    u_perm[(k & 255) * 16 + (k >> 8)] = uu;
}

__device__ __forceinline__ void lgkm_fence() {
    asm volatile("s_waitcnt lgkmcnt(0)" ::: "memory");
    __builtin_amdgcn_sched_barrier(0);
}

__device__ __forceinline__ void load_pair(float4 a0[4], float4 a1[4],
                                          const float* __restrict__ x,
                                          size_t b0, size_t b1, int t) {
    const float4* p0 = reinterpret_cast<const float4*>(x + b0 + t * 16);
    const float4* p1 = reinterpret_cast<const float4*>(x + b1 + t * 16);
#pragma unroll
    for (int c = 0; c < 4; ++c) { a0[c] = p0[c]; a1[c] = p1[c]; }
}

// LDS layout in f2 units: A(c2,c1,c0) = c2*256 + c1*16 + (c0 ^ (c1 & 14)).
// Measured (R5/R6): SQ_LDS_BANK_CONFLICT == 256 cyc/block (trivial).
// Cross-pair slab reuse is same-wave DS-FIFO-ordered; the two barriers per
// pair separate all cross-wave accesses (hazard analysis in R5 notes).

__device__ __forceinline__ void pair_body(const float4 a0[4], const float4 a1[4],
                                          const float4 s2r[4],
                                          f2* __restrict__ lds,
                                          const float* __restrict__ s1,
                                          const float* __restrict__ u_perm,
                                          float* __restrict__ out,
                                          size_t b0, size_t b1, bool r1_valid,
                                          int t, int P, int Q) {
    f2 v[16];
    // ---- pack + s2 scale. First VMEM wait of the body: needs x (oldest)
    //      and s2 (pre-loop) -> vmcnt(8), the 8 prefetch loads stay alive.
#pragma unroll
    for (int c = 0; c < 4; ++c) {
        float4 a = a0[c], b = a1[c], s = s2r[c];
        v[4 * c + 0] = f2{a.x * s.x, b.x * s.x};
        v[4 * c + 1] = f2{a.y * s.y, b.y * s.y};
        v[4 * c + 2] = f2{a.z * s.z, b.z * s.z};
        v[4 * c + 3] = f2{a.w * s.w, b.w * s.w};
    }

    // ---- pass 1: digit d0 ----
    fwht16(v);

    // u_perm loads issued here (after the prefetch in program order); first
    // use is ~1500 cyc later, by which time the prefetch has retired anyway.
    const float4* upv = reinterpret_cast<const float4*>(u_perm + t * 16);
    float4 upr[4];
#pragma unroll
    for (int c = 0; c < 4; ++c) upr[c] = upv[c];

    // ---- rot1 (wave-local): write (P,Q,j) b128, read (P,j,Q) b64 ----
#pragma unroll
    for (int c = 0; c < 8; ++c) {
        int a4 = P * 256 + Q * 16 + ((2 * c) ^ (Q & 14));
        *reinterpret_cast<float4*>(&lds[a4]) =
            make_float4(v[2 * c].x, v[2 * c].y, v[2 * c + 1].x, v[2 * c + 1].y);
    }
    lgkm_fence();
#pragma unroll
    for (int j = 0; j < 16; ++j)
        v[j] = lds[P * 256 + j * 16 + (Q ^ (j & 14))];

    // ---- pass 2: digit d1 ----
    fwht16(v);

    // ---- rot2: write back same addrs (same-thread WAR), bar, read cross ----
#pragma unroll
    for (int j = 0; j < 16; ++j)
        lds[P * 256 + j * 16 + (Q ^ (j & 14))] = v[j];
    __syncthreads();
#pragma unroll
    for (int j = 0; j < 16; ++j)
        v[j] = lds[j * 256 + P * 16 + (Q ^ (P & 14))];

    // ---- pass 3: digit d2 -> FWHT#1 done; v[j] = y[j*256 + t] ----
    fwht16(v);

    // ---- diagonal u: u_perm[t*16+j] == u[j*256+t] ----
#pragma unroll
    for (int c = 0; c < 4; ++c) {
        v[4 * c + 0] *= upr[c].x;
        v[4 * c + 1] *= upr[c].y;
        v[4 * c + 2] *= upr[c].z;
        v[4 * c + 3] *= upr[c].w;
    }

    // ---- pass 4: digit e2 ----
    fwht16(v);

    // s1 loads issued mid-body, first use at the store (~1000+ cyc later).
    const float4* s1v = reinterpret_cast<const float4*>(s1 + t * 16);
    float4 s1r[4];
#pragma unroll
    for (int c = 0; c < 4; ++c) s1r[c] = s1v[c];

    // ---- rot3: write cross (same addrs as rot2-read), bar, read local ----
#pragma unroll
    for (int j = 0; j < 16; ++j)
        lds[j * 256 + P * 16 + (Q ^ (P & 14))] = v[j];
    __syncthreads();
#pragma unroll
    for (int j = 0; j < 16; ++j)
        v[j] = lds[P * 256 + j * 16 + (Q ^ (j & 14))];

    // ---- pass 5: digit e1 ----
    fwht16(v);

    // ---- rot4 (wave-local): write back, fence, read (P,Q,j) b128 ----
#pragma unroll
    for (int j = 0; j < 16; ++j)
        lds[P * 256 + j * 16 + (Q ^ (j & 14))] = v[j];
    lgkm_fence();
#pragma unroll
    for (int c = 0; c < 8; ++c) {
        int a4 = P * 256 + Q * 16 + ((2 * c) ^ (Q & 14));
        float4 tt = *reinterpret_cast<const float4*>(&lds[a4]);
        v[2 * c]     = f2{tt.x, tt.y};
        v[2 * c + 1] = f2{tt.z, tt.w};
    }

    // ---- pass 6: digit e0 -> natural order, element 16t + j ----
    fwht16(v);

    // ---- s1 scale + store both rows ----
    {
        float4* o0 = reinterpret_cast<float4*>(out + b0 + t * 16);
        float4* o1 = reinterpret_cast<float4*>(out + b1 + t * 16);
#pragma unroll
        for (int c = 0; c < 4; ++c) {
            float4 s = s1r[c];
            o0[c] = make_float4(v[4 * c + 0].x * s.x, v[4 * c + 1].x * s.y,
                                v[4 * c + 2].x * s.z, v[4 * c + 3].x * s.w);
            if (r1_valid)
                o1[c] = make_float4(v[4 * c + 0].y * s.x, v[4 * c + 1].y * s.y,
                                    v[4 * c + 2].y * s.z, v[4 * c + 3].y * s.w);
        }
    }
}

__global__ __launch_bounds__(256)
void whvi_persist_kernel(const float* __restrict__ x,
                         const float* __restrict__ s1,
                         const float* __restrict__ s2,
                         const float* __restrict__ u_perm,
                         float* __restrict__ out,
                         int nrows) {
    __shared__ __align__(16) f2 lds[WHVI_D];  // 32 KB

    const int t = threadIdx.x;
    const int P = t >> 4;
    const int Q = t & 15;
    const int npairs = (nrows + 1) >> 1;

    int p = blockIdx.x;
    if (p >= npairs) return;

    auto bases = [&](int pr, size_t& b0, size_t& b1, bool& rv) {
        int r0 = pr * 2;
        rv = (r0 + 1 < nrows);
        b0 = (size_t)r0 * WHVI_D;
        b1 = (size_t)(r0 + (rv ? 1 : 0)) * WHVI_D;
    };

    // s2: loaded ONCE, before any x load -> oldest in the vmem queue; every
    // pack-wait therefore retires {x, s2} while leaving the prefetch alive.
    float4 s2r[4];
    {
        const float4* s2v = reinterpret_cast<const float4*>(s2 + t * 16);
#pragma unroll
        for (int c = 0; c < 4; ++c) s2r[c] = s2v[c];
    }

    float4 A0[4], A1[4], B0[4], B1[4];
    size_t b0, b1; bool rv;
    bases(p, b0, b1, rv);
    load_pair(A0, A1, x, b0, b1, t);

    bool useA = true;
    for (;;) {
        int pn = p + NBLK;
        size_t nb0 = 0, nb1 = 0; bool nrv = false;
        if (pn < npairs) {
            bases(pn, nb0, nb1, nrv);
            // Prefetch AFTER s2/current-x (older), BEFORE the body issues
            // anything it waits on early -> survives the pack wait.
            if (useA) load_pair(B0, B1, x, nb0, nb1, t);
            else      load_pair(A0, A1, x, nb0, nb1, t);
        }
        if (useA) pair_body(A0, A1, s2r, lds, s1, u_perm, out, b0, b1, rv, t, P, Q);
        else      pair_body(B0, B1, s2r, lds, s1, u_perm, out, b0, b1, rv, t, P, Q);
        if (pn >= npairs) break;
        p = pn; b0 = nb0; b1 = nb1; rv = nrv; useA = !useA;
    }
}

extern "C" void kernel_launch(void* const* d_in, const int* in_sizes, int n_in,
                              void* d_out, int out_size, void* d_ws, size_t ws_size,
                              hipStream_t stream) {
    const float* x     = (const float*)d_in[0];
    const float* s1    = (const float*)d_in[1];
    const float* s2    = (const float*)d_in[2];
    const float* g_mu  = (const float*)d_in[3];
    const float* g_rho = (const float*)d_in[4];
    const float* g_eps = (const float*)d_in[5];
    // d_in[6] is H — unused; the FWHT realizes it exactly.
    float* out = (float*)d_out;

    const int nrows = in_sizes[0] / WHVI_D;  // 8192

    float* u_perm = (float*)d_ws;  // 16 KB of workspace
    u_precompute_kernel<<<WHVI_D / 256, 256, 0, stream>>>(g_mu, g_rho, g_eps, u_perm);

    const int npairs = (nrows + 1) / 2;
    const int nblk = npairs < NBLK ? npairs : NBLK;
    whvi_persist_kernel<<<nblk, 256, 0, stream>>>(x, s1, s2, u_perm, out, nrows);
}

// Round 8
// 68.203 us; speedup vs baseline: 1.0658x; 1.0480x over previous
//
#include <hip/hip_runtime.h>
#include <hip/hip_bf16.h>
#include <math.h>

// out[n,:] = s1 .* FWHT( (u/4096) .* FWHT( s2 .* x[n,:] ) ),
// u = g_mu + softplus(g_rho)*epsilon, FWHT = unnormalized Walsh-Hadamard.
//
// R8: single-row radix-16, 256 threads/block, 16 KB LDS -> 8 blocks/CU
// (32 waves/CU static, the HW cap). Combines R1's high residency with R5's
// cost reductions: u-precompute (no per-thread softplus), b128 I/O, and a
// 3-term XOR-swizzled LDS layout making every rotation pattern conflict-free
// (b32: 2 lanes/bank = free; b128: balanced at the 8/bank minimum):
//   A(c2,c1,c0) = c2*256 + (c1^(c2&1))*16 + (c0 ^ (c1&12) ^ ((c2&3)<<2))
// Storage invariant: A(a,b,c) holds the element with digits (d2=a,d1=b,d0=c).
// rot1/rot4 are wave-local (reader and writer share t>>6 — proof: addresses
// A(P,*,Q) are written/read only by threads with the same P>>2); rot2/rot3
// cross waves -> the only two __syncthreads per row.

#define WHVI_D 4096

__global__ __launch_bounds__(256)
void u_precompute_kernel(const float* __restrict__ g_mu,
                         const float* __restrict__ g_rho,
                         const float* __restrict__ g_eps,
                         float* __restrict__ u_perm) {
    int k = blockIdx.x * 256 + threadIdx.x;  // 0..4095, coalesced
    float rho = g_rho[k];
    float sp = fmaxf(rho, 0.0f) + __logf(1.0f + __expf(-fabsf(rho)));
    float uu = (g_mu[k] + sp * g_eps[k]) * (1.0f / 4096.0f);
    // u index k = j*256 + t  ->  store at t*16 + j (per-thread contiguous)
    u_perm[(k & 255) * 16 + (k >> 8)] = uu;
}

__device__ __forceinline__ void fwht16(float v[16]) {
#pragma unroll
    for (int s = 1; s < 16; s <<= 1) {
#pragma unroll
        for (int i = 0; i < 16; ++i) {
            if ((i & s) == 0) {
                float a = v[i], b = v[i | s];
                v[i] = a + b;
                v[i | s] = a - b;
            }
        }
    }
}

__device__ __forceinline__ void lgkm_fence() {
    asm volatile("s_waitcnt lgkmcnt(0)" ::: "memory");
    __builtin_amdgcn_sched_barrier(0);
}

__device__ __forceinline__ int lds_addr(int c2, int c1, int c0) {
    return c2 * 256 + ((c1 ^ (c2 & 1)) << 4) + (c0 ^ (c1 & 12) ^ ((c2 & 3) << 2));
}

__global__ __launch_bounds__(256)
void whvi_row_kernel(const float* __restrict__ x,
                     const float* __restrict__ s1,
                     const float* __restrict__ s2,
                     const float* __restrict__ u_perm,
                     float* __restrict__ out,
                     int nrows) {
    __shared__ __align__(16) float lds[WHVI_D];  // 16 KB

    const int t = threadIdx.x;   // 0..255
    const int P = t >> 4;        // 0..15
    const int Q = t & 15;        // 0..15
    const int row = blockIdx.x;
    if (row >= nrows) return;
    const size_t base = (size_t)row * WHVI_D;

    float v[16];

    // ---- load x[row, t*16 + 0..15] and s2, scale (b128, coalesced) ----
    {
        const float4* xv = reinterpret_cast<const float4*>(x + base + t * 16);
        const float4* sv = reinterpret_cast<const float4*>(s2 + t * 16);
#pragma unroll
        for (int c = 0; c < 4; ++c) {
            float4 a = xv[c], s = sv[c];
            v[4 * c + 0] = a.x * s.x;
            v[4 * c + 1] = a.y * s.y;
            v[4 * c + 2] = a.z * s.z;
            v[4 * c + 3] = a.w * s.w;
        }
    }

    // ---- pass 1: digit d0 (regs) ----
    fwht16(v);

    // ---- rot1 (wave-local): write (P,Q,4c..) b128, fence, read (P,j,Q) b32 ----
#pragma unroll
    for (int c = 0; c < 4; ++c) {
        int a0 = lds_addr(P, Q, 4 * c);  // low 2 bits of swizzle untouched -> aligned
        *reinterpret_cast<float4*>(&lds[a0]) =
            make_float4(v[4 * c + 0], v[4 * c + 1], v[4 * c + 2], v[4 * c + 3]);
    }
    lgkm_fence();
#pragma unroll
    for (int j = 0; j < 16; ++j)
        v[j] = lds[lds_addr(P, j, Q)];

    // ---- pass 2: digit d1 ----
    fwht16(v);

    // ---- rot2: write back same addrs (same-thread WAR), bar, read (j,P,Q) ----
#pragma unroll
    for (int j = 0; j < 16; ++j)
        lds[lds_addr(P, j, Q)] = v[j];
    __syncthreads();
#pragma unroll
    for (int j = 0; j < 16; ++j)
        v[j] = lds[lds_addr(j, P, Q)];

    // ---- pass 3: digit d2 -> FWHT#1 done; v[j] = y[j*256 + t] ----
    fwht16(v);

    // ---- diagonal u: u_perm[t*16+j] == u[j*256+t] (b128, L2-hot) ----
    {
        const float4* upv = reinterpret_cast<const float4*>(u_perm + t * 16);
#pragma unroll
        for (int c = 0; c < 4; ++c) {
            float4 uu = upv[c];
            v[4 * c + 0] *= uu.x;
            v[4 * c + 1] *= uu.y;
            v[4 * c + 2] *= uu.z;
            v[4 * c + 3] *= uu.w;
        }
    }

    // ---- pass 4: digit e2 (already in regs) ----
    fwht16(v);

    // ---- rot3: write (j,P,Q) (same addrs as rot2-read), bar, read (P,j,Q) ----
#pragma unroll
    for (int j = 0; j < 16; ++j)
        lds[lds_addr(j, P, Q)] = v[j];
    __syncthreads();
#pragma unroll
    for (int j = 0; j < 16; ++j)
        v[j] = lds[lds_addr(P, j, Q)];

    // ---- pass 5: digit e1 ----
    fwht16(v);

    // ---- rot4 (wave-local): write back same addrs, fence, read (P,Q,*) b128 ----
#pragma unroll
    for (int j = 0; j < 16; ++j)
        lds[lds_addr(P, j, Q)] = v[j];
    lgkm_fence();
#pragma unroll
    for (int c = 0; c < 4; ++c) {
        int a0 = lds_addr(P, Q, 4 * c);
        float4 tt = *reinterpret_cast<const float4*>(&lds[a0]);
        v[4 * c + 0] = tt.x;
        v[4 * c + 1] = tt.y;
        v[4 * c + 2] = tt.z;
        v[4 * c + 3] = tt.w;
    }

    // ---- pass 6: digit e0 -> natural order, element t*16 + j ----
    fwht16(v);

    // ---- s1 scale + store (b128, coalesced) ----
    {
        const float4* sv = reinterpret_cast<const float4*>(s1 + t * 16);
        float4* ov = reinterpret_cast<float4*>(out + base + t * 16);
#pragma unroll
        for (int c = 0; c < 4; ++c) {
            float4 s = sv[c];
            ov[c] = make_float4(v[4 * c + 0] * s.x, v[4 * c + 1] * s.y,
                                v[4 * c + 2] * s.z, v[4 * c + 3] * s.w);
        }
    }
}

extern "C" void kernel_launch(void* const* d_in, const int* in_sizes, int n_in,
                              void* d_out, int out_size, void* d_ws, size_t ws_size,
                              hipStream_t stream) {
    const float* x     = (const float*)d_in[0];
    const float* s1    = (const float*)d_in[1];
    const float* s2    = (const float*)d_in[2];
    const float* g_mu  = (const float*)d_in[3];
    const float* g_rho = (const float*)d_in[4];
    const float* g_eps = (const float*)d_in[5];
    // d_in[6] is H — unused; the FWHT realizes it exactly.
    float* out = (float*)d_out;

    const int nrows = in_sizes[0] / WHVI_D;  // 8192

    float* u_perm = (float*)d_ws;  // 16 KB of workspace
    u_precompute_kernel<<<WHVI_D / 256, 256, 0, stream>>>(g_mu, g_rho, g_eps, u_perm);

    whvi_row_kernel<<<nrows, 256, 0, stream>>>(x, s1, s2, u_perm, out, nrows);
}